// Round 14
// baseline (340.520 us; speedup 1.0000x reference)
//
#include <hip/hip_runtime.h>

#define NN 100000
#define NE 1600000
#define NG 512
#define HID 128
#define FPD 2048
#define BSHIFT 8
#define NBUK ((NN + 255) >> 8)   // 391
#define BCAP 5120
#define EPB 4096
#define EPT 16
#define COLSCAP (NE + NBUK * 4096 + 64)
#define AGG_BLOCKS 2048
#define AGG_WAVES (AGG_BLOCKS * 4)

typedef _Float16 f16;
typedef __attribute__((ext_vector_type(8))) _Float16 f16x8;
typedef __attribute__((ext_vector_type(2))) _Float16 f16x2;
typedef __attribute__((ext_vector_type(4))) float f32x4;

// ---------------- bucketed CSR build (packed: (dst&255)<<24 | src) ----------------

__global__ __launch_bounds__(256) void bucket_scatter(const int* __restrict__ src,
                                                      const int* __restrict__ dst,
                                                      int* __restrict__ bcnt,
                                                      uint* __restrict__ bbuf, int E) {
  __shared__ int hist[NBUK];
  __shared__ int gbase[NBUK];
  __shared__ int lbase[NBUK + 1];
  __shared__ int sc[2][512];
  __shared__ uint stage[EPB];
  int t = threadIdx.x;
  int e0 = blockIdx.x * EPB;
  for (int i = t; i < NBUK; i += 256) hist[i] = 0;
  __syncthreads();

  int myb[EPT], myoff[EPT];
  uint myp[EPT];
#pragma unroll
  for (int u = 0; u < EPT; ++u) {
    int e = e0 + u * 256 + t;
    myb[u] = -1;
    if (e < E) {
      int d = dst[e];
      int b = d >> BSHIFT;
      myp[u] = ((uint)(d & 255) << 24) | (uint)src[e];
      myb[u] = b;
      myoff[u] = atomicAdd(&hist[b], 1);
    }
  }
  __syncthreads();

  sc[0][t] = (t < NBUK) ? hist[t] : 0;
  sc[0][t + 256] = (t + 256 < NBUK) ? hist[t + 256] : 0;
  int pp = 0;
  for (int off = 1; off < 512; off <<= 1) {
    __syncthreads();
    int a0 = sc[pp][t] + ((t >= off) ? sc[pp][t - off] : 0);
    int a1 = sc[pp][t + 256] + ((t + 256 >= off) ? sc[pp][t + 256 - off] : 0);
    sc[1 - pp][t] = a0;
    sc[1 - pp][t + 256] = a1;
    pp = 1 - pp;
  }
  __syncthreads();
  if (t < NBUK) lbase[t] = (t == 0) ? 0 : sc[pp][t - 1];
  if (t + 256 < NBUK) lbase[t + 256] = sc[pp][t + 255];
  if (t == 0) lbase[NBUK] = sc[pp][NBUK - 1];
  for (int i = t; i < NBUK; i += 256)
    if (hist[i] > 0) gbase[i] = atomicAdd(&bcnt[i], hist[i]);
  __syncthreads();

#pragma unroll
  for (int u = 0; u < EPT; ++u)
    if (myb[u] >= 0) stage[lbase[myb[u]] + myoff[u]] = myp[u];
  __syncthreads();

  int total = lbase[NBUK];
  for (int j = t; j < total; j += 256) {
    int lo = 0, hi = NBUK - 1;
    while (lo < hi) {
      int mid = (lo + hi + 1) >> 1;
      if (lbase[mid] <= j) lo = mid; else hi = mid - 1;
    }
    bbuf[(size_t)lo * BCAP + gbase[lo] + (j - lbase[lo])] = stage[j];
  }
}

// 1 block: exclusive scan of (bcnt[b] + 4096) -> bbase (padded bucket bases)
__global__ __launch_bounds__(512) void scan_bcnt(const int* __restrict__ bcnt,
                                                 int* __restrict__ bbase) {
  __shared__ int lds[512];
  int t = threadIdx.x;
  int v = (t < NBUK) ? (bcnt[t] + 4096) : 0;
  lds[t] = v;
  __syncthreads();
  for (int off = 1; off < 512; off <<= 1) {
    int add = (t >= off) ? lds[t - off] : 0;
    __syncthreads();
    lds[t] += add;
    __syncthreads();
  }
  if (t < NBUK) bbase[t] = lds[t] - v;
}

// per bucket: stage entries in LDS, hist + padded scan -> astart/aend, place cols + pads
__global__ __launch_bounds__(256) void bucket_finish(const int* __restrict__ bcnt,
                                                     const uint* __restrict__ bbuf,
                                                     const int* __restrict__ bbase,
                                                     int* __restrict__ astart,
                                                     int* __restrict__ aend,
                                                     int* __restrict__ cols) {
  __shared__ uint ebuf[BCAP];
  __shared__ int h[256];
  __shared__ int s2[256];
  __shared__ int cur[256];
  int b = blockIdx.x, t = threadIdx.x;
  h[t] = 0;
  __syncthreads();
  int n = bcnt[b];
  const uint* bb = bbuf + (size_t)b * BCAP;
  for (int e = t; e < n; e += 256) {
    uint w = bb[e];
    ebuf[e] = w;
    atomicAdd(&h[w >> 24], 1);
  }
  __syncthreads();
  int v = h[t];
  int pv = (v + 15) & ~15;   // padded length (multiple of 16)
  s2[t] = pv;
  __syncthreads();
  for (int off = 1; off < 256; off <<= 1) {
    int add = (t >= off) ? s2[t - off] : 0;
    __syncthreads();
    s2[t] += add;
    __syncthreads();
  }
  int base = bbase[b] + s2[t] - pv;
  int node = (b << BSHIFT) + t;
  if (node < NN) {
    astart[node] = base;
    aend[node] = base + pv;
  }
  cur[t] = base;
  __syncthreads();
  for (int e = t; e < n; e += 256) {
    uint w = ebuf[e];
    int pos = atomicAdd(&cur[w >> 24], 1);
    cols[pos] = (int)(w & 0xFFFFFF);
  }
  // pads -> zero row NN
  for (int p = v; p < pv; ++p) cols[base + p] = NN;
}

// ---------------- conversions (weights only) ----------------

__global__ __launch_bounds__(256) void cvt_all(const float* __restrict__ w0,
                                               const float* __restrict__ w1,
                                               const float* __restrict__ w2,
                                               const float* __restrict__ w3,
                                               const float* __restrict__ w4,
                                               const float* __restrict__ Wfp,
                                               f16* __restrict__ Wt,
                                               f16* __restrict__ Wfpt) {
  int idx = blockIdx.x * 256 + threadIdx.x;
  if (idx < 81920) {
    int w = idx >> 14, rem = idx & 16383;
    int j = rem >> 7, k = rem & 127;
    const float* W = (w == 0) ? w0 : (w == 1) ? w1 : (w == 2) ? w2 : (w == 3) ? w3 : w4;
    Wt[idx] = (f16)W[k * 128 + j];
  } else if (idx < 344064) {
    int id = idx - 81920;
    int j = id >> 11, k = id & 2047;
    Wfpt[id] = (f16)Wfp[k * 128 + j];
  }
}

// ---------------- aggregation: persistent waves, pure 16-edge loop ----------------
// Fixed grid (2048 blocks x 4 waves = 32 waves/CU). Wave w handles nodes w, w+8192, ...
// Per node: branch-free padded 16-edge loop, 4 independent uint4 loads/lane.

__global__ __launch_bounds__(256) void agg_f16(const f16* __restrict__ H,
                                               const int* __restrict__ astart,
                                               const int* __restrict__ aend,
                                               const int* __restrict__ cols,
                                               f16* __restrict__ out) {
  int wid = blockIdx.x * 4 + (threadIdx.x >> 6);
  int lane = threadIdx.x & 63;
  int q = lane >> 4;
  int sub = lane & 15;
  union U { uint4 u; f16x2 h2[4]; f16 h[8]; };

  for (int node = wid; node < NN; node += AGG_WAVES) {
    int s = astart[node], e = aend[node];
    float acc[8] = {0.f, 0.f, 0.f, 0.f, 0.f, 0.f, 0.f, 0.f};

    for (int i = s; i < e; i += 16) {
      int c0 = cols[i + q];
      int c1 = cols[i + 4 + q];
      int c2 = cols[i + 8 + q];
      int c3 = cols[i + 12 + q];
      U v0, v1, v2, v3;
      v0.u = *reinterpret_cast<const uint4*>(&H[(size_t)c0 * 128 + sub * 8]);
      v1.u = *reinterpret_cast<const uint4*>(&H[(size_t)c1 * 128 + sub * 8]);
      v2.u = *reinterpret_cast<const uint4*>(&H[(size_t)c2 * 128 + sub * 8]);
      v3.u = *reinterpret_cast<const uint4*>(&H[(size_t)c3 * 128 + sub * 8]);
#pragma unroll
      for (int p = 0; p < 4; ++p) {
        f16x2 t01 = v0.h2[p] + v1.h2[p];
        f16x2 t23 = v2.h2[p] + v3.h2[p];
        f16x2 tt = t01 + t23;
        acc[2 * p]     += (float)tt[0];
        acc[2 * p + 1] += (float)tt[1];
      }
    }

#pragma unroll
    for (int z = 0; z < 8; ++z) {
      acc[z] += __shfl_xor(acc[z], 16);
      acc[z] += __shfl_xor(acc[z], 32);
    }
    if (q == 0) {
      union { uint4 u; f16 h[8]; } pk;
#pragma unroll
      for (int z = 0; z < 8; ++z) pk.h[z] = (f16)acc[z];
      *reinterpret_cast<uint4*>(&out[(size_t)node * 128 + sub * 8]) = pk.u;
    }
  }
}

// ---------------- pre_mp: h0 = prelu(x_f32 @ W_pre + b), fused convert, 64 rows/block ----------------

__global__ __launch_bounds__(256) void gemm_pre(const float* __restrict__ X,
                                                const f16* __restrict__ Wt,
                                                const float* __restrict__ bias,
                                                const float* __restrict__ pa,
                                                f16* __restrict__ out, int rows) {
  int t = threadIdx.x;
  int wave = t >> 6, lane = t & 63;
  int lrow = lane & 15, lk = lane >> 4;
  int r0 = blockIdx.x * 64;
  int n0 = wave << 1;

  const f16x8* Wv = reinterpret_cast<const f16x8*>(Wt);
  f16x8 w[2][4];
#pragma unroll
  for (int ni = 0; ni < 2; ++ni)
#pragma unroll
    for (int ks = 0; ks < 4; ++ks)
      w[ni][ks] = Wv[((((n0 + ni) << 4) + lrow) << 4) + (ks << 2) + lk];

  float bv[2], av[2];
#pragma unroll
  for (int ni = 0; ni < 2; ++ni) {
    int col = ((n0 + ni) << 4) + lrow;
    bv[ni] = bias[col];
    av[ni] = pa[col];
  }

#pragma unroll 2
  for (int rg = 0; rg < 4; ++rg) {
    int r = r0 + (rg << 4) + lrow;
    if (r > rows - 1) r = rows - 1;
    const float* xp = X + (size_t)r * 128 + (lk << 3);
    f16x8 a[4];
#pragma unroll
    for (int ks = 0; ks < 4; ++ks) {
      float4 v0 = *reinterpret_cast<const float4*>(xp + (ks << 5));
      float4 v1 = *reinterpret_cast<const float4*>(xp + (ks << 5) + 4);
      f16x8 av8;
      av8[0] = (f16)v0.x; av8[1] = (f16)v0.y; av8[2] = (f16)v0.z; av8[3] = (f16)v0.w;
      av8[4] = (f16)v1.x; av8[5] = (f16)v1.y; av8[6] = (f16)v1.z; av8[7] = (f16)v1.w;
      a[ks] = av8;
    }
    f32x4 acc[2] = {(f32x4){0.f, 0.f, 0.f, 0.f}, (f32x4){0.f, 0.f, 0.f, 0.f}};
#pragma unroll
    for (int ks = 0; ks < 4; ++ks)
#pragma unroll
      for (int ni = 0; ni < 2; ++ni)
        acc[ni] = __builtin_amdgcn_mfma_f32_16x16x32_f16(a[ks], w[ni][ks], acc[ni], 0, 0, 0);
#pragma unroll
    for (int ni = 0; ni < 2; ++ni) {
      int col = ((n0 + ni) << 4) + lrow;
#pragma unroll
      for (int j = 0; j < 4; ++j) {
        int rr = r0 + (rg << 4) + (lk << 2) + j;
        if (rr < rows) {
          float xv = acc[ni][j] + bv[ni];
          xv = xv > 0.f ? xv : av[ni] * xv;
          out[(size_t)rr * 128 + col] = (f16)xv;
        }
      }
    }
  }
}

// ---------------- dual fp16 MFMA GEMM, W-stationary, dbuf A, 64 rows/block ----------------

__global__ __launch_bounds__(256) void gemm_f16(const f16* __restrict__ A1,
                                                const f16* __restrict__ A2,
                                                const f16* __restrict__ W1t,
                                                const f16* __restrict__ W2t,
                                                const float* __restrict__ bias,
                                                const float* __restrict__ pa,
                                                f16* __restrict__ Ch, int rows) {
  int t = threadIdx.x;
  int wave = t >> 6, lane = t & 63;
  int lrow = lane & 15, lk = lane >> 4;
  int r0 = blockIdx.x * 64;
  int n0 = wave << 1;

  const f16x8* Wv1 = reinterpret_cast<const f16x8*>(W1t);
  const f16x8* Wv2 = reinterpret_cast<const f16x8*>(W2t);

  f16x8 w1[2][4], w2[2][4];
#pragma unroll
  for (int ni = 0; ni < 2; ++ni)
#pragma unroll
    for (int ks = 0; ks < 4; ++ks) {
      int wi = ((((n0 + ni) << 4) + lrow) << 4) + (ks << 2) + lk;
      w1[ni][ks] = Wv1[wi];
      w2[ni][ks] = Wv2[wi];
    }

  float bv[2], av[2];
#pragma unroll
  for (int ni = 0; ni < 2; ++ni) {
    int col = ((n0 + ni) << 4) + lrow;
    bv[ni] = bias[col];
    av[ni] = pa[col];
  }

  f16x8 aA[2][4], aB[2][4];
  {
    int r = r0 + lrow;
    if (r > rows - 1) r = rows - 1;
    size_t off = (size_t)r * 128 + (lk << 3);
#pragma unroll
    for (int ks = 0; ks < 4; ++ks) {
      aA[0][ks] = *reinterpret_cast<const f16x8*>(A1 + off + (ks << 5));
      aB[0][ks] = *reinterpret_cast<const f16x8*>(A2 + off + (ks << 5));
    }
  }

#pragma unroll
  for (int rg = 0; rg < 4; ++rg) {
    int cur = rg & 1, nxt = cur ^ 1;
    if (rg < 3) {
      int rn = r0 + ((rg + 1) << 4) + lrow;
      if (rn > rows - 1) rn = rows - 1;
      size_t offn = (size_t)rn * 128 + (lk << 3);
#pragma unroll
      for (int ks = 0; ks < 4; ++ks) {
        aA[nxt][ks] = *reinterpret_cast<const f16x8*>(A1 + offn + (ks << 5));
        aB[nxt][ks] = *reinterpret_cast<const f16x8*>(A2 + offn + (ks << 5));
      }
    }
    f32x4 acc1[2] = {(f32x4){0.f, 0.f, 0.f, 0.f}, (f32x4){0.f, 0.f, 0.f, 0.f}};
    f32x4 acc2[2] = {(f32x4){0.f, 0.f, 0.f, 0.f}, (f32x4){0.f, 0.f, 0.f, 0.f}};
#pragma unroll
    for (int ks = 0; ks < 4; ++ks) {
#pragma unroll
      for (int ni = 0; ni < 2; ++ni) {
        acc1[ni] = __builtin_amdgcn_mfma_f32_16x16x32_f16(aA[cur][ks], w1[ni][ks], acc1[ni], 0, 0, 0);
        acc2[ni] = __builtin_amdgcn_mfma_f32_16x16x32_f16(aB[cur][ks], w2[ni][ks], acc2[ni], 0, 0, 0);
      }
    }
#pragma unroll
    for (int ni = 0; ni < 2; ++ni) {
      int col = ((n0 + ni) << 4) + lrow;
#pragma unroll
      for (int j = 0; j < 4; ++j) {
        int rr = r0 + (rg << 4) + (lk << 2) + j;
        if (rr < rows) {
          float xv = acc1[ni][j] + acc2[ni][j] + bv[ni];
          xv = xv > 0.f ? xv : av[ni] * xv;
          Ch[(size_t)rr * 128 + col] = (f16)xv;
        }
      }
    }
  }
}

// ---------------- fingerprint head GEMM (K-split, reads fp f32 directly) ----------------

__global__ __launch_bounds__(256) void fp_gemm(const float* __restrict__ FP,
                                               const f16* __restrict__ Wt,
                                               float* __restrict__ part) {
  int kc = blockIdx.x;   // 0..15
  int rb = blockIdx.y;   // 0..3
  int t = threadIdx.x;
  int wave = t >> 6, lane = t & 63;
  int lrow = lane & 15, lk = lane >> 4;
  int r0 = rb * 128;
  int n0 = wave << 1;

  const f16x8* Wv = reinterpret_cast<const f16x8*>(Wt);

  f16x8 w[2][4];
#pragma unroll
  for (int ni = 0; ni < 2; ++ni)
#pragma unroll
    for (int ks = 0; ks < 4; ++ks) {
      int j = ((n0 + ni) << 4) + lrow;
      w[ni][ks] = Wv[j * 256 + (kc << 4) + (ks << 2) + lk];
    }

#pragma unroll 2
  for (int rg = 0; rg < 8; ++rg) {
    int r = r0 + (rg << 4) + lrow;
    const float* xp = FP + (size_t)r * 2048 + (kc << 7) + (lk << 3);
    f16x8 a[4];
#pragma unroll
    for (int ks = 0; ks < 4; ++ks) {
      float4 v0 = *reinterpret_cast<const float4*>(xp + (ks << 5));
      float4 v1 = *reinterpret_cast<const float4*>(xp + (ks << 5) + 4);
      f16x8 av8;
      av8[0] = (f16)v0.x; av8[1] = (f16)v0.y; av8[2] = (f16)v0.z; av8[3] = (f16)v0.w;
      av8[4] = (f16)v1.x; av8[5] = (f16)v1.y; av8[6] = (f16)v1.z; av8[7] = (f16)v1.w;
      a[ks] = av8;
    }
    f32x4 acc[2] = {(f32x4){0.f, 0.f, 0.f, 0.f}, (f32x4){0.f, 0.f, 0.f, 0.f}};
#pragma unroll
    for (int ks = 0; ks < 4; ++ks)
#pragma unroll
      for (int ni = 0; ni < 2; ++ni)
        acc[ni] = __builtin_amdgcn_mfma_f32_16x16x32_f16(a[ks], w[ni][ks], acc[ni], 0, 0, 0);
#pragma unroll
    for (int ni = 0; ni < 2; ++ni) {
      int col = ((n0 + ni) << 4) + lrow;
#pragma unroll
      for (int j = 0; j < 4; ++j) {
        int rr = r0 + (rg << 4) + (lk << 2) + j;
        part[((size_t)kc * 512 + rr) * 128 + col] = acc[ni][j];
      }
    }
  }
}

// ---------------- fused pool + fp-finish + final ----------------

__device__ __forceinline__ int lower_bound_dev(const int* __restrict__ arr, int n, int val) {
  int lo = 0, hi = n;
  while (lo < hi) {
    int mid = (lo + hi) >> 1;
    if (arr[mid] < val) lo = mid + 1; else hi = mid;
  }
  return lo;
}

__global__ __launch_bounds__(512) void pool_final(const f16* __restrict__ H,
                                                  const int* __restrict__ batch,
                                                  const float* __restrict__ part,
                                                  const float* __restrict__ bfp,
                                                  const float* __restrict__ afp,
                                                  const float* __restrict__ Wp,
                                                  const float* __restrict__ bp,
                                                  float* __restrict__ out) {
  __shared__ float red[512];
  __shared__ float pf[256];
  int g = blockIdx.x;
  int t = threadIdx.x;
  int col = t & 127, rq = t >> 7;
  int start = lower_bound_dev(batch, NN, g);
  int end = lower_bound_dev(batch, NN, g + 1);
  float acc = 0.f;
  for (int r = start + rq; r < end; r += 4) acc += (float)H[(size_t)r * 128 + col];
  red[t] = acc;
  __syncthreads();
  if (t < 128) {
    float s = red[t] + red[128 + t] + red[256 + t] + red[384 + t];
    int c = end - start;
    pf[t] = s / (float)(c > 0 ? c : 1);
  } else if (t < 256) {
    int j = t - 128;
    float s = bfp[j];
#pragma unroll
    for (int kc = 0; kc < 16; ++kc) s += part[((size_t)kc * 512 + g) * 128 + j];
    float a = afp[j];
    pf[t] = s > 0.f ? s : a * s;
  }
  __syncthreads();
  if (t < 128) {
    float v = pf[t] * Wp[t] + pf[128 + t] * Wp[128 + t];
    red[t] = v;
  }
  __syncthreads();
  if (t < 64) {
    float v = red[t] + red[t + 64];
    for (int off = 32; off > 0; off >>= 1) v += __shfl_down(v, off);
    if (t == 0) out[g] = v + bp[0];
  }
}

// ---------------- launch ----------------

extern "C" void kernel_launch(void* const* d_in, const int* in_sizes, int n_in,
                              void* d_out, int out_size, void* d_ws, size_t ws_size,
                              hipStream_t stream) {
  const float* x      = (const float*)d_in[0];
  const float* fp     = (const float*)d_in[1];
  const int*   ei     = (const int*)d_in[2];
  const int*   batch  = (const int*)d_in[3];
  const float* W_pre  = (const float*)d_in[4];
  const float* b_pre  = (const float*)d_in[5];
  const float* a_pre  = (const float*)d_in[6];
  const float* Wl1    = (const float*)d_in[7];
  const float* bl1    = (const float*)d_in[8];
  const float* Wr1    = (const float*)d_in[9];
  const float* a1     = (const float*)d_in[10];
  const float* Wl2    = (const float*)d_in[11];
  const float* bl2    = (const float*)d_in[12];
  const float* Wr2    = (const float*)d_in[13];
  const float* a2     = (const float*)d_in[14];
  const float* W_fp   = (const float*)d_in[15];
  const float* b_fp   = (const float*)d_in[16];
  const float* a_fp   = (const float*)d_in[17];
  const float* W_post = (const float*)d_in[18];
  const float* b_post = (const float*)d_in[19];

  const int* src = ei;
  const int* dst = ei + NE;

  const size_t NBUF = (size_t)(NN + 1) * 128;  // +1 zero row
  f16* bufA = (f16*)d_ws;                // h0 -> h2
  f16* bufB = bufA + NBUF;               // h1
  f16* bufC = bufB + NBUF;               // agg output
  f16* Wt   = bufC + NBUF;               // 5*16384
  f16* Wfpt = Wt + 5 * 16384;            // 128*2048
  float* part = (float*)(Wfpt + 128 * 2048);  // 16*512*128 fp32
  int* astart  = (int*)(part + 16 * 512 * 128);  // NN
  int* aend    = astart + NN;            // NN
  int* bbase   = aend + NN;              // NBUK (pad)
  int* bcnt    = bbase + NBUK + 4;       // NBUK (pad)
  int* colsA   = bcnt + ((NBUK + 3) & ~3);  // COLSCAP
  uint* bbuf   = (uint*)(colsA + COLSCAP);  // NBUK*BCAP*4B = 8MB

  // --- CSR build (dst -> srcs), rows padded to x16 with zero-row NN ---
  hipMemsetAsync(bcnt, 0, NBUK * sizeof(int), stream);
  hipMemsetAsync(bufA + (size_t)NN * 128, 0, 256, stream);  // zero row for gathers
  hipMemsetAsync(bufB + (size_t)NN * 128, 0, 256, stream);
  bucket_scatter<<<(NE + EPB - 1) / EPB, 256, 0, stream>>>(src, dst, bcnt, bbuf, NE);
  scan_bcnt<<<1, 512, 0, stream>>>(bcnt, bbase);
  bucket_finish<<<NBUK, 256, 0, stream>>>(bcnt, bbuf, bbase, astart, aend, colsA);

  // --- conversions + fp path ---
  cvt_all<<<(344064 + 255) / 256, 256, 0, stream>>>(W_pre, Wl1, Wr1, Wl2, Wr2, W_fp,
                                                    Wt, Wfpt);
  {
    dim3 g(16, 4);
    fp_gemm<<<g, 256, 0, stream>>>(fp, Wfpt, part);
  }

  const f16* Wt_pre = Wt;
  const f16* Wt_l1  = Wt + 16384;
  const f16* Wt_r1  = Wt + 32768;
  const f16* Wt_l2  = Wt + 49152;
  const f16* Wt_r2  = Wt + 65536;

  int gGemm = (NN + 63) / 64;  // 1563

  // pre_mp: h0 = prelu(x@W_pre + b_pre) -> bufA (reads x fp32 directly)
  gemm_pre<<<gGemm, 256, 0, stream>>>(x, Wt_pre, b_pre, a_pre, bufA, NN);

  // conv1: agg(h0) -> bufC; h1 = prelu(agg@Wl1 + h0@Wr1 + bl1) -> bufB
  agg_f16<<<AGG_BLOCKS, 256, 0, stream>>>(bufA, astart, aend, colsA, bufC);
  gemm_f16<<<gGemm, 256, 0, stream>>>(bufC, bufA, Wt_l1, Wt_r1, bl1, a1, bufB, NN);

  // conv2: agg(h1) -> bufC; h2 = prelu(agg@Wl2 + h1@Wr2 + bl2) -> bufA
  agg_f16<<<AGG_BLOCKS, 256, 0, stream>>>(bufB, astart, aend, colsA, bufC);
  gemm_f16<<<gGemm, 256, 0, stream>>>(bufC, bufB, Wt_l2, Wt_r2, bl2, a2, bufA, NN);

  // fused pool + fp-finish + final
  pool_final<<<NG, 512, 0, stream>>>(bufA, batch, part, b_fp, a_fp, W_post, b_post,
                                     (float*)d_out);
}

// Round 15
// 329.525 us; speedup vs baseline: 1.0334x; 1.0334x over previous
//
#include <hip/hip_runtime.h>

#define NN 100000
#define NE 1600000
#define NG 512
#define HID 128
#define FPD 2048
#define BSHIFT 8
#define NBUK ((NN + 255) >> 8)   // 391
#define BCAP 5120
#define EPB 4096
#define EPT 16

typedef _Float16 f16;
typedef __attribute__((ext_vector_type(8))) _Float16 f16x8;
typedef __attribute__((ext_vector_type(2))) _Float16 f16x2;
typedef __attribute__((ext_vector_type(4))) float f32x4;

// ---------------- bucketed CSR build (packed: (dst&255)<<24 | src) ----------------

__global__ __launch_bounds__(256) void bucket_scatter(const int* __restrict__ src,
                                                      const int* __restrict__ dst,
                                                      int* __restrict__ bcnt,
                                                      uint* __restrict__ bbuf, int E) {
  __shared__ int hist[NBUK];
  __shared__ int gbase[NBUK];
  __shared__ int lbase[NBUK + 1];
  __shared__ int sc[2][512];
  __shared__ uint stage[EPB];
  int t = threadIdx.x;
  int e0 = blockIdx.x * EPB;
  for (int i = t; i < NBUK; i += 256) hist[i] = 0;
  __syncthreads();

  int myb[EPT], myoff[EPT];
  uint myp[EPT];
#pragma unroll
  for (int u = 0; u < EPT; ++u) {
    int e = e0 + u * 256 + t;
    myb[u] = -1;
    if (e < E) {
      int d = dst[e];
      int b = d >> BSHIFT;
      myp[u] = ((uint)(d & 255) << 24) | (uint)src[e];
      myb[u] = b;
      myoff[u] = atomicAdd(&hist[b], 1);
    }
  }
  __syncthreads();

  sc[0][t] = (t < NBUK) ? hist[t] : 0;
  sc[0][t + 256] = (t + 256 < NBUK) ? hist[t + 256] : 0;
  int pp = 0;
  for (int off = 1; off < 512; off <<= 1) {
    __syncthreads();
    int a0 = sc[pp][t] + ((t >= off) ? sc[pp][t - off] : 0);
    int a1 = sc[pp][t + 256] + ((t + 256 >= off) ? sc[pp][t + 256 - off] : 0);
    sc[1 - pp][t] = a0;
    sc[1 - pp][t + 256] = a1;
    pp = 1 - pp;
  }
  __syncthreads();
  if (t < NBUK) lbase[t] = (t == 0) ? 0 : sc[pp][t - 1];
  if (t + 256 < NBUK) lbase[t + 256] = sc[pp][t + 255];
  if (t == 0) lbase[NBUK] = sc[pp][NBUK - 1];
  for (int i = t; i < NBUK; i += 256)
    if (hist[i] > 0) gbase[i] = atomicAdd(&bcnt[i], hist[i]);
  __syncthreads();

#pragma unroll
  for (int u = 0; u < EPT; ++u)
    if (myb[u] >= 0) stage[lbase[myb[u]] + myoff[u]] = myp[u];
  __syncthreads();

  int total = lbase[NBUK];
  for (int j = t; j < total; j += 256) {
    int lo = 0, hi = NBUK - 1;
    while (lo < hi) {
      int mid = (lo + hi + 1) >> 1;
      if (lbase[mid] <= j) lo = mid; else hi = mid - 1;
    }
    bbuf[(size_t)lo * BCAP + gbase[lo] + (j - lbase[lo])] = stage[j];
  }
}

// 1 block: exclusive scan of bcnt[0..NBUK) -> bbase; also rowptr[NN] = total
__global__ __launch_bounds__(512) void scan_bcnt(const int* __restrict__ bcnt,
                                                 int* __restrict__ bbase,
                                                 int* __restrict__ rowptr) {
  __shared__ int lds[512];
  int t = threadIdx.x;
  int v = (t < NBUK) ? bcnt[t] : 0;
  lds[t] = v;
  __syncthreads();
  for (int off = 1; off < 512; off <<= 1) {
    int add = (t >= off) ? lds[t - off] : 0;
    __syncthreads();
    lds[t] += add;
    __syncthreads();
  }
  if (t < NBUK) bbase[t] = lds[t] - v;
  if (t == 0) {
    bbase[NBUK] = lds[511];
    rowptr[NN] = lds[511];
  }
}

// per bucket: stage entries in LDS, hist + scan -> rowptr, then place cols
__global__ __launch_bounds__(256) void bucket_finish(const int* __restrict__ bcnt,
                                                     const uint* __restrict__ bbuf,
                                                     const int* __restrict__ bbase,
                                                     int* __restrict__ rowptr,
                                                     int* __restrict__ cols) {
  __shared__ uint ebuf[BCAP];
  __shared__ int h[256];
  __shared__ int s2[256];
  __shared__ int cur[256];
  int b = blockIdx.x, t = threadIdx.x;
  h[t] = 0;
  __syncthreads();
  int n = bcnt[b];
  const uint* bb = bbuf + (size_t)b * BCAP;
  for (int e = t; e < n; e += 256) {
    uint w = bb[e];
    ebuf[e] = w;
    atomicAdd(&h[w >> 24], 1);
  }
  __syncthreads();
  int v = h[t];
  s2[t] = v;
  __syncthreads();
  for (int off = 1; off < 256; off <<= 1) {
    int add = (t >= off) ? s2[t - off] : 0;
    __syncthreads();
    s2[t] += add;
    __syncthreads();
  }
  int base = bbase[b] + s2[t] - v;
  int node = (b << BSHIFT) + t;
  if (node < NN) rowptr[node] = base;
  cur[t] = base;
  __syncthreads();
  for (int e = t; e < n; e += 256) {
    uint w = ebuf[e];
    int pos = atomicAdd(&cur[w >> 24], 1);
    cols[pos] = (int)(w & 0xFFFFFF);
  }
}

// ---------------- fused conversions ----------------

__global__ __launch_bounds__(256) void cvt_all(const float* __restrict__ w0,
                                               const float* __restrict__ w1,
                                               const float* __restrict__ w2,
                                               const float* __restrict__ w3,
                                               const float* __restrict__ w4,
                                               const float* __restrict__ Wfp,
                                               const float* __restrict__ fp,
                                               f16* __restrict__ Wt,
                                               f16* __restrict__ Wfpt,
                                               f16* __restrict__ fpb) {
  int idx = blockIdx.x * 256 + threadIdx.x;
  if (idx < 81920) {
    int w = idx >> 14, rem = idx & 16383;
    int j = rem >> 7, k = rem & 127;
    const float* W = (w == 0) ? w0 : (w == 1) ? w1 : (w == 2) ? w2 : (w == 3) ? w3 : w4;
    Wt[idx] = (f16)W[k * 128 + j];
  } else if (idx < 344064) {
    int id = idx - 81920;
    int j = id >> 11, k = id & 2047;
    Wfpt[id] = (f16)Wfp[k * 128 + j];
  } else if (idx < 606208) {
    int id = idx - 344064;
    float4 v = *reinterpret_cast<const float4*>(&fp[id * 4]);
    union { uint2 u; f16 h[4]; } o;
    o.h[0] = (f16)v.x; o.h[1] = (f16)v.y; o.h[2] = (f16)v.z; o.h[3] = (f16)v.w;
    *reinterpret_cast<uint2*>(&fpb[id * 4]) = o.u;
  }
}

// ---------------- aggregation: 16-edge unroll, pk_add_f16 tree, uint4 loads ----------------

__global__ __launch_bounds__(256) void agg_f16(const f16* __restrict__ H,
                                               const int* __restrict__ rowptr,
                                               const int* __restrict__ cols,
                                               f16* __restrict__ out) {
  int node = blockIdx.x * 4 + (threadIdx.x >> 6);
  int lane = threadIdx.x & 63;
  int q = lane >> 4;
  int sub = lane & 15;
  int s = rowptr[node], e = rowptr[node + 1];
  float acc[8] = {0.f, 0.f, 0.f, 0.f, 0.f, 0.f, 0.f, 0.f};
  union U { uint4 u; f16x2 h2[4]; f16 h[8]; };

  int i = s;
  for (; i + 15 < e; i += 16) {
    int c0 = cols[i + q];
    int c1 = cols[i + 4 + q];
    int c2 = cols[i + 8 + q];
    int c3 = cols[i + 12 + q];
    U v0, v1, v2, v3;
    v0.u = *reinterpret_cast<const uint4*>(&H[(size_t)c0 * 128 + sub * 8]);
    v1.u = *reinterpret_cast<const uint4*>(&H[(size_t)c1 * 128 + sub * 8]);
    v2.u = *reinterpret_cast<const uint4*>(&H[(size_t)c2 * 128 + sub * 8]);
    v3.u = *reinterpret_cast<const uint4*>(&H[(size_t)c3 * 128 + sub * 8]);
#pragma unroll
    for (int p = 0; p < 4; ++p) {
      f16x2 t01 = v0.h2[p] + v1.h2[p];
      f16x2 t23 = v2.h2[p] + v3.h2[p];
      f16x2 tt = t01 + t23;
      acc[2 * p]     += (float)tt[0];
      acc[2 * p + 1] += (float)tt[1];
    }
  }
  for (; i < e; i += 4) {
    int rem = e - i;
    if (q < rem) {
      U v;
      v.u = *reinterpret_cast<const uint4*>(&H[(size_t)cols[i + q] * 128 + sub * 8]);
#pragma unroll
      for (int z = 0; z < 8; ++z) acc[z] += (float)v.h[z];
    }
  }

#pragma unroll
  for (int z = 0; z < 8; ++z) {
    acc[z] += __shfl_xor(acc[z], 16);
    acc[z] += __shfl_xor(acc[z], 32);
  }
  if (q == 0) {
    union { uint4 u; f16 h[8]; } pk;
#pragma unroll
    for (int z = 0; z < 8; ++z) pk.h[z] = (f16)acc[z];
    *reinterpret_cast<uint4*>(&out[(size_t)node * 128 + sub * 8]) = pk.u;
  }
}

// ---------------- pre_mp: h0 = prelu(x_f32 @ W_pre + b), fused convert, 64 rows/block ----------------

__global__ __launch_bounds__(256) void gemm_pre(const float* __restrict__ X,
                                                const f16* __restrict__ Wt,
                                                const float* __restrict__ bias,
                                                const float* __restrict__ pa,
                                                f16* __restrict__ out, int rows) {
  int t = threadIdx.x;
  int wave = t >> 6, lane = t & 63;
  int lrow = lane & 15, lk = lane >> 4;
  int r0 = blockIdx.x * 64;
  int n0 = wave << 1;

  const f16x8* Wv = reinterpret_cast<const f16x8*>(Wt);
  f16x8 w[2][4];
#pragma unroll
  for (int ni = 0; ni < 2; ++ni)
#pragma unroll
    for (int ks = 0; ks < 4; ++ks)
      w[ni][ks] = Wv[((((n0 + ni) << 4) + lrow) << 4) + (ks << 2) + lk];

  float bv[2], av[2];
#pragma unroll
  for (int ni = 0; ni < 2; ++ni) {
    int col = ((n0 + ni) << 4) + lrow;
    bv[ni] = bias[col];
    av[ni] = pa[col];
  }

#pragma unroll 2
  for (int rg = 0; rg < 4; ++rg) {
    int r = r0 + (rg << 4) + lrow;
    if (r > rows - 1) r = rows - 1;
    const float* xp = X + (size_t)r * 128 + (lk << 3);
    f16x8 a[4];
#pragma unroll
    for (int ks = 0; ks < 4; ++ks) {
      float4 v0 = *reinterpret_cast<const float4*>(xp + (ks << 5));
      float4 v1 = *reinterpret_cast<const float4*>(xp + (ks << 5) + 4);
      f16x8 av8;
      av8[0] = (f16)v0.x; av8[1] = (f16)v0.y; av8[2] = (f16)v0.z; av8[3] = (f16)v0.w;
      av8[4] = (f16)v1.x; av8[5] = (f16)v1.y; av8[6] = (f16)v1.z; av8[7] = (f16)v1.w;
      a[ks] = av8;
    }
    f32x4 acc[2] = {(f32x4){0.f, 0.f, 0.f, 0.f}, (f32x4){0.f, 0.f, 0.f, 0.f}};
#pragma unroll
    for (int ks = 0; ks < 4; ++ks)
#pragma unroll
      for (int ni = 0; ni < 2; ++ni)
        acc[ni] = __builtin_amdgcn_mfma_f32_16x16x32_f16(a[ks], w[ni][ks], acc[ni], 0, 0, 0);
#pragma unroll
    for (int ni = 0; ni < 2; ++ni) {
      int col = ((n0 + ni) << 4) + lrow;
#pragma unroll
      for (int j = 0; j < 4; ++j) {
        int rr = r0 + (rg << 4) + (lk << 2) + j;
        if (rr < rows) {
          float xv = acc[ni][j] + bv[ni];
          xv = xv > 0.f ? xv : av[ni] * xv;
          out[(size_t)rr * 128 + col] = (f16)xv;
        }
      }
    }
  }
}

// ---------------- dual fp16 MFMA GEMM, W-stationary, dbuf A, 64 rows/block ----------------

__global__ __launch_bounds__(256) void gemm_f16(const f16* __restrict__ A1,
                                                const f16* __restrict__ A2,
                                                const f16* __restrict__ W1t,
                                                const f16* __restrict__ W2t,
                                                const float* __restrict__ bias,
                                                const float* __restrict__ pa,
                                                f16* __restrict__ Ch, int rows) {
  int t = threadIdx.x;
  int wave = t >> 6, lane = t & 63;
  int lrow = lane & 15, lk = lane >> 4;
  int r0 = blockIdx.x * 64;
  int n0 = wave << 1;

  const f16x8* Wv1 = reinterpret_cast<const f16x8*>(W1t);
  const f16x8* Wv2 = reinterpret_cast<const f16x8*>(W2t);

  f16x8 w1[2][4], w2[2][4];
#pragma unroll
  for (int ni = 0; ni < 2; ++ni)
#pragma unroll
    for (int ks = 0; ks < 4; ++ks) {
      int wi = ((((n0 + ni) << 4) + lrow) << 4) + (ks << 2) + lk;
      w1[ni][ks] = Wv1[wi];
      w2[ni][ks] = Wv2[wi];
    }

  float bv[2], av[2];
#pragma unroll
  for (int ni = 0; ni < 2; ++ni) {
    int col = ((n0 + ni) << 4) + lrow;
    bv[ni] = bias[col];
    av[ni] = pa[col];
  }

  f16x8 aA[2][4], aB[2][4];
  {
    int r = r0 + lrow;
    if (r > rows - 1) r = rows - 1;
    size_t off = (size_t)r * 128 + (lk << 3);
#pragma unroll
    for (int ks = 0; ks < 4; ++ks) {
      aA[0][ks] = *reinterpret_cast<const f16x8*>(A1 + off + (ks << 5));
      aB[0][ks] = *reinterpret_cast<const f16x8*>(A2 + off + (ks << 5));
    }
  }

#pragma unroll
  for (int rg = 0; rg < 4; ++rg) {
    int cur = rg & 1, nxt = cur ^ 1;
    if (rg < 3) {
      int rn = r0 + ((rg + 1) << 4) + lrow;
      if (rn > rows - 1) rn = rows - 1;
      size_t offn = (size_t)rn * 128 + (lk << 3);
#pragma unroll
      for (int ks = 0; ks < 4; ++ks) {
        aA[nxt][ks] = *reinterpret_cast<const f16x8*>(A1 + offn + (ks << 5));
        aB[nxt][ks] = *reinterpret_cast<const f16x8*>(A2 + offn + (ks << 5));
      }
    }
    f32x4 acc1[2] = {(f32x4){0.f, 0.f, 0.f, 0.f}, (f32x4){0.f, 0.f, 0.f, 0.f}};
    f32x4 acc2[2] = {(f32x4){0.f, 0.f, 0.f, 0.f}, (f32x4){0.f, 0.f, 0.f, 0.f}};
#pragma unroll
    for (int ks = 0; ks < 4; ++ks) {
#pragma unroll
      for (int ni = 0; ni < 2; ++ni) {
        acc1[ni] = __builtin_amdgcn_mfma_f32_16x16x32_f16(aA[cur][ks], w1[ni][ks], acc1[ni], 0, 0, 0);
        acc2[ni] = __builtin_amdgcn_mfma_f32_16x16x32_f16(aB[cur][ks], w2[ni][ks], acc2[ni], 0, 0, 0);
      }
    }
#pragma unroll
    for (int ni = 0; ni < 2; ++ni) {
      int col = ((n0 + ni) << 4) + lrow;
#pragma unroll
      for (int j = 0; j < 4; ++j) {
        int rr = r0 + (rg << 4) + (lk << 2) + j;
        if (rr < rows) {
          float xv = acc1[ni][j] + acc2[ni][j] + bv[ni];
          xv = xv > 0.f ? xv : av[ni] * xv;
          Ch[(size_t)rr * 128 + col] = (f16)xv;
        }
      }
    }
  }
}

// ---------------- fingerprint head GEMM (K-split, partials) ----------------

__global__ __launch_bounds__(256) void fp_gemm(const f16* __restrict__ A,
                                               const f16* __restrict__ Wt,
                                               float* __restrict__ part) {
  int kc = blockIdx.x;   // 0..15
  int rb = blockIdx.y;   // 0..3
  int t = threadIdx.x;
  int wave = t >> 6, lane = t & 63;
  int lrow = lane & 15, lk = lane >> 4;
  int r0 = rb * 128;
  int n0 = wave << 1;

  const f16x8* Wv = reinterpret_cast<const f16x8*>(Wt);
  const f16x8* Av = reinterpret_cast<const f16x8*>(A);

  f16x8 w[2][4];
#pragma unroll
  for (int ni = 0; ni < 2; ++ni)
#pragma unroll
    for (int ks = 0; ks < 4; ++ks) {
      int j = ((n0 + ni) << 4) + lrow;
      w[ni][ks] = Wv[j * 256 + (kc << 4) + (ks << 2) + lk];
    }

#pragma unroll 2
  for (int rg = 0; rg < 8; ++rg) {
    int r = r0 + (rg << 4) + lrow;
    f16x8 a[4];
#pragma unroll
    for (int ks = 0; ks < 4; ++ks)
      a[ks] = Av[r * 256 + (kc << 4) + (ks << 2) + lk];
    f32x4 acc[2] = {(f32x4){0.f, 0.f, 0.f, 0.f}, (f32x4){0.f, 0.f, 0.f, 0.f}};
#pragma unroll
    for (int ks = 0; ks < 4; ++ks)
#pragma unroll
      for (int ni = 0; ni < 2; ++ni)
        acc[ni] = __builtin_amdgcn_mfma_f32_16x16x32_f16(a[ks], w[ni][ks], acc[ni], 0, 0, 0);
#pragma unroll
    for (int ni = 0; ni < 2; ++ni) {
      int col = ((n0 + ni) << 4) + lrow;
#pragma unroll
      for (int j = 0; j < 4; ++j) {
        int rr = r0 + (rg << 4) + (lk << 2) + j;
        part[((size_t)kc * 512 + rr) * 128 + col] = acc[ni][j];
      }
    }
  }
}

// ---------------- fused pool + fp-finish + final ----------------

__device__ __forceinline__ int lower_bound_dev(const int* __restrict__ arr, int n, int val) {
  int lo = 0, hi = n;
  while (lo < hi) {
    int mid = (lo + hi) >> 1;
    if (arr[mid] < val) lo = mid + 1; else hi = mid;
  }
  return lo;
}

__global__ __launch_bounds__(512) void pool_final(const f16* __restrict__ H,
                                                  const int* __restrict__ batch,
                                                  const float* __restrict__ part,
                                                  const float* __restrict__ bfp,
                                                  const float* __restrict__ afp,
                                                  const float* __restrict__ Wp,
                                                  const float* __restrict__ bp,
                                                  float* __restrict__ out) {
  __shared__ float red[512];
  __shared__ float pf[256];
  int g = blockIdx.x;
  int t = threadIdx.x;
  int col = t & 127, rq = t >> 7;
  int start = lower_bound_dev(batch, NN, g);
  int end = lower_bound_dev(batch, NN, g + 1);
  float acc = 0.f;
  for (int r = start + rq; r < end; r += 4) acc += (float)H[(size_t)r * 128 + col];
  red[t] = acc;
  __syncthreads();
  if (t < 128) {
    float s = red[t] + red[128 + t] + red[256 + t] + red[384 + t];
    int c = end - start;
    pf[t] = s / (float)(c > 0 ? c : 1);
  } else if (t < 256) {
    int j = t - 128;
    float s = bfp[j];
#pragma unroll
    for (int kc = 0; kc < 16; ++kc) s += part[((size_t)kc * 512 + g) * 128 + j];
    float a = afp[j];
    pf[t] = s > 0.f ? s : a * s;
  }
  __syncthreads();
  if (t < 128) {
    float v = pf[t] * Wp[t] + pf[128 + t] * Wp[128 + t];
    red[t] = v;
  }
  __syncthreads();
  if (t < 64) {
    float v = red[t] + red[t + 64];
    for (int off = 32; off > 0; off >>= 1) v += __shfl_down(v, off);
    if (t == 0) out[g] = v + bp[0];
  }
}

// ---------------- launch ----------------

extern "C" void kernel_launch(void* const* d_in, const int* in_sizes, int n_in,
                              void* d_out, int out_size, void* d_ws, size_t ws_size,
                              hipStream_t stream) {
  const float* x      = (const float*)d_in[0];
  const float* fp     = (const float*)d_in[1];
  const int*   ei     = (const int*)d_in[2];
  const int*   batch  = (const int*)d_in[3];
  const float* W_pre  = (const float*)d_in[4];
  const float* b_pre  = (const float*)d_in[5];
  const float* a_pre  = (const float*)d_in[6];
  const float* Wl1    = (const float*)d_in[7];
  const float* bl1    = (const float*)d_in[8];
  const float* Wr1    = (const float*)d_in[9];
  const float* a1     = (const float*)d_in[10];
  const float* Wl2    = (const float*)d_in[11];
  const float* bl2    = (const float*)d_in[12];
  const float* Wr2    = (const float*)d_in[13];
  const float* a2     = (const float*)d_in[14];
  const float* W_fp   = (const float*)d_in[15];
  const float* b_fp   = (const float*)d_in[16];
  const float* a_fp   = (const float*)d_in[17];
  const float* W_post = (const float*)d_in[18];
  const float* b_post = (const float*)d_in[19];

  const int* src = ei;
  const int* dst = ei + NE;

  const size_t NBUF = (size_t)NN * 128;
  f16* bufA = (f16*)d_ws;                // h0 -> h2
  f16* bufB = bufA + NBUF;               // h1
  f16* bufC = bufB + NBUF;               // agg output
  f16* Wt   = bufC + NBUF;               // 5*16384
  f16* fpb  = Wt + 5 * 16384;            // 512*2048
  f16* Wfpt = fpb + 512 * 2048;          // 128*2048
  float* part = (float*)(Wfpt + 128 * 2048);  // 16*512*128 fp32
  int* rowptr  = (int*)(part + 16 * 512 * 128);  // NN+1 (pad 4)
  int* bbase   = rowptr + NN + 4;        // NBUK+1 (pad)
  int* bcnt    = bbase + NBUK + 4;       // NBUK (pad)
  int* colsA   = bcnt + ((NBUK + 3) & ~3);  // NE
  uint* bbuf   = (uint*)(colsA + NE);    // NBUK*BCAP*4B = 8MB

  // --- CSR build (dst -> srcs) ---
  hipMemsetAsync(bcnt, 0, NBUK * sizeof(int), stream);
  bucket_scatter<<<(NE + EPB - 1) / EPB, 256, 0, stream>>>(src, dst, bcnt, bbuf, NE);
  scan_bcnt<<<1, 512, 0, stream>>>(bcnt, bbase, rowptr);
  bucket_finish<<<NBUK, 256, 0, stream>>>(bcnt, bbuf, bbase, rowptr, colsA);

  // --- conversions + fp path ---
  cvt_all<<<(606208 + 255) / 256, 256, 0, stream>>>(W_pre, Wl1, Wr1, Wl2, Wr2, W_fp, fp,
                                                    Wt, Wfpt, fpb);
  {
    dim3 g(16, 4);
    fp_gemm<<<g, 256, 0, stream>>>(fpb, Wfpt, part);
  }

  const f16* Wt_pre = Wt;
  const f16* Wt_l1  = Wt + 16384;
  const f16* Wt_r1  = Wt + 32768;
  const f16* Wt_l2  = Wt + 49152;
  const f16* Wt_r2  = Wt + 65536;

  int gGemm = (NN + 63) / 64;  // 1563

  // pre_mp: h0 = prelu(x@W_pre + b_pre) -> bufA (reads x fp32 directly)
  gemm_pre<<<gGemm, 256, 0, stream>>>(x, Wt_pre, b_pre, a_pre, bufA, NN);

  // conv1: agg(h0) -> bufC; h1 = prelu(agg@Wl1 + h0@Wr1 + bl1) -> bufB
  agg_f16<<<NN / 4, 256, 0, stream>>>(bufA, rowptr, colsA, bufC);
  gemm_f16<<<gGemm, 256, 0, stream>>>(bufC, bufA, Wt_l1, Wt_r1, bl1, a1, bufB, NN);

  // conv2: agg(h1) -> bufC; h2 = prelu(agg@Wl2 + h1@Wr2 + bl2) -> bufA
  agg_f16<<<NN / 4, 256, 0, stream>>>(bufB, rowptr, colsA, bufC);
  gemm_f16<<<gGemm, 256, 0, stream>>>(bufC, bufB, Wt_l2, Wt_r2, bl2, a2, bufA, NN);

  // fused pool + fp-finish + final
  pool_final<<<NG, 512, 0, stream>>>(bufA, batch, part, b_fp, a_fp, W_post, b_post,
                                     (float*)d_out);
}